// Round 12
// baseline (160.143 us; speedup 1.0000x reference)
//
#include <hip/hip_runtime.h>
#include <math.h>

typedef unsigned short u16;
typedef short bf16x8 __attribute__((ext_vector_type(8)));
typedef float f32x4 __attribute__((ext_vector_type(4)));

#define FW_ 180
#define FH_ 180
#define HW_ (FW_*FH_)
#define CIN_ 128
#define BB_ 4
#define MM_ 500
#define PW_ 182
#define PADE ((size_t)BB_*PW_*PW_*CIN_)

// d_out segment offsets (floats), in reference return order
#define HM_OFF   0
#define REG_OFF  (BB_*2*HW_)
#define HEAT_OFF (REG_OFF + BB_*9*HW_)
#define RB_OFF   (HEAT_OFF + BB_*2*HW_)
#define IND_OFF  (RB_OFF + BB_*MM_*5*8)
#define MSK_OFF  (IND_OFF + BB_*MM_*5)
#define HMM_OFF  (MSK_OFF + BB_*MM_*5)

__device__ inline u16 f2bf(float f) {
    unsigned u = __float_as_uint(f);
    u += 0x7FFFu + ((u >> 16) & 1u);           // RNE
    return (u16)(u >> 16);
}

#define GLOAD_LDS16(gsrc, ldst) \
    __builtin_amdgcn_global_load_lds( \
        (const __attribute__((address_space(1))) unsigned*)(gsrc), \
        (__attribute__((address_space(3))) unsigned*)(ldst), 16, 0, 0)

// ---------------------------------------------------------------------------
// merged init: zero padded-buffer borders + zero heatmap + weight transposes
// ---------------------------------------------------------------------------
__global__ void k_init_w(u16* __restrict__ ws, float* __restrict__ out,
                         const float* __restrict__ w1, const float* __restrict__ w2,
                         const float* __restrict__ hw, const float* __restrict__ rw,
                         u16* __restrict__ wT1, u16* __restrict__ wT2,
                         u16* __restrict__ wTh)
{
    int idx = blockIdx.x * 256 + threadIdx.x;
    const int n1 = 3 * BB_ * PW_ * PW_;
    const int n2 = n1 + BB_ * 2 * HW_;
    const int NW = 9 * CIN_ * CIN_;
    const int n3 = n2 + NW;
    const int n4 = n3 + NW;
    const int n5 = n4 + 9 * 16 * CIN_;
    if (idx < n1) {
        int buf = idx / (BB_ * PW_ * PW_);
        int rem = idx % (BB_ * PW_ * PW_);
        int p = rem % (PW_ * PW_);
        int r = p / PW_, c = p % PW_;
        if (r > 0 && r < PW_ - 1 && c > 0 && c < PW_ - 1) return;
        u16* base = ws + (size_t)buf * PADE + (size_t)rem * CIN_;
#pragma unroll
        for (int i = 0; i < 16; ++i) ((uint4*)base)[i] = make_uint4(0, 0, 0, 0);
    } else if (idx < n2) {
        out[HEAT_OFF + (idx - n1)] = 0.f;
    } else if (idx < n3) {
        int j = idx - n2;
        int tap = j / (CIN_ * CIN_);
        int r = j % (CIN_ * CIN_);
        int co = r >> 7, ci = r & 127;
        wT1[j] = f2bf(w1[((size_t)co * CIN_ + ci) * 9 + tap]);
    } else if (idx < n4) {
        int j = idx - n3;
        int tap = j / (CIN_ * CIN_);
        int r = j % (CIN_ * CIN_);
        int co = r >> 7, ci = r & 127;
        wT2[j] = f2bf(w2[((size_t)co * CIN_ + ci) * 9 + tap]);
    } else if (idx < n5) {
        int j = idx - n4;
        int tap = j / (16 * CIN_);
        int r = j % (16 * CIN_);
        int co = r >> 7, ci = r & 127;
        float v = 0.f;
        if (co < 2)       v = hw[((size_t)co * CIN_ + ci) * 9 + tap];
        else if (co < 11) v = rw[((size_t)(co - 2) * CIN_ + ci) * 9 + tap];
        wTh[j] = f2bf(v);
    }
}

// ---------------------------------------------------------------------------
// x (f32 NCHW) -> xT (bf16 [b][row+1][col+1][ci] padded); 16B stores
// ---------------------------------------------------------------------------
__global__ __launch_bounds__(256) void k_prep_xT(const float* __restrict__ in,
                                                 u16* __restrict__ xT)
{
    __shared__ unsigned lt32[180 * 65];        // [col][ci2] packed 2xbf16
    int tid = threadIdx.x;
    int row = blockIdx.x, b = blockIdx.y;
    const float* inr = in + ((size_t)b * CIN_ * FH_ + row) * FW_;
    for (int i = tid; i < 64 * 45; i += 256) {
        int ci2 = i / 45, c4 = i - 45 * ci2;
        const float* p0 = inr + (size_t)(2 * ci2) * HW_ + c4 * 4;
        float4 a = *(const float4*)p0;
        float4 bq = *(const float4*)(p0 + HW_);
        lt32[(c4 * 4 + 0) * 65 + ci2] = (unsigned)f2bf(a.x) | ((unsigned)f2bf(bq.x) << 16);
        lt32[(c4 * 4 + 1) * 65 + ci2] = (unsigned)f2bf(a.y) | ((unsigned)f2bf(bq.y) << 16);
        lt32[(c4 * 4 + 2) * 65 + ci2] = (unsigned)f2bf(a.z) | ((unsigned)f2bf(bq.z) << 16);
        lt32[(c4 * 4 + 3) * 65 + ci2] = (unsigned)f2bf(a.w) | ((unsigned)f2bf(bq.w) << 16);
    }
    __syncthreads();
    unsigned* dst = (unsigned*)(xT + ((size_t)b * PW_ * PW_ + (size_t)(row + 1) * PW_ + 1) * CIN_);
    for (int idx = tid; idx < 180 * 16; idx += 256) {
        int col = idx >> 4, q = idx & 15;
        uint4 v;
        v.x = lt32[col * 65 + q * 4 + 0];
        v.y = lt32[col * 65 + q * 4 + 1];
        v.z = lt32[col * 65 + q * 4 + 2];
        v.w = lt32[col * 65 + q * 4 + 3];
        *(uint4*)&dst[col * 64 + q * 4] = v;
    }
}

// ---------------------------------------------------------------------------
// conv 3x3 SAME 128->128 + BN + ReLU.
// Wave tile widened: 64co x 8rows x 16cols = 4 m-frags x 8 n-frags.
// Per tap: 4 A + 8 B ds_reads -> 32 MFMA (ratio 2.67 vs 2.0): total
// ds_reads/conv 1.24M -> 954k, and 96-MFMA straight-line runs per phase.
// Block: 4 waves (cols split), tile 64co x 8r x 64c. LDS = input halo
// 10x66x32 (42.2 KB) + weights dbuf 2x12.3 KB = 66.8 KB -> 2 blocks/CU.
// Weight stage prefetched one phase ahead; 4 barriers/chunk.
// Grid 552 = 8x69 -> bijective XCD swizzle (FETCH stays L2-local, r11).
// ---------------------------------------------------------------------------
__global__ __launch_bounds__(256, 2) void k_conv_v12(
    const u16* __restrict__ xT, const u16* __restrict__ wT,
    const float* __restrict__ gg, const float* __restrict__ bbn,
    const float* __restrict__ mmn, const float* __restrict__ vvn,
    u16* __restrict__ yT)
{
    __shared__ u16 lin[2640 * 8];        // 42.2 KB: 10 x 66 x 32ci halo
    __shared__ u16 lwt[2][768 * 8];      // 2 x 12.3 KB: 3 taps x 64co x 32ci

    int tid  = threadIdx.x;
    int wv   = tid >> 6, lane = tid & 63;
    int lm   = lane & 15, hi = lane >> 4;

    // XCD swizzle: 552 blocks = 8 XCDs x 69 (bijective)
    int wg   = blockIdx.x;
    int wgid = (wg & 7) * 69 + (wg >> 3);
    int b    = wgid / 138;
    int rem  = wgid % 138;
    int rt   = rem / 6;
    int t6   = rem % 6;
    int csp  = t6 % 3, cog = t6 / 3;
    int C0   = (csp == 2) ? 116 : csp * 64;
    int cob  = cog * 64;
    int R0   = (rt == 22) ? 172 : rt * 8;
    const u16* xb = xT + (size_t)b * PW_ * PW_ * CIN_;

    f32x4 acc[4][8];                     // [mf][row]
#pragma unroll
    for (int i = 0; i < 4; ++i)
#pragma unroll
        for (int j = 0; j < 8; ++j) acc[i][j] = (f32x4){0.f, 0.f, 0.f, 0.f};

    // weight staging source offset (one tap per round)
    const int wco = tid >> 2;
    const int wq  = (tid & 3) ^ ((wco >> 1) & 3);
    const unsigned soffW = (unsigned)((cob + wco) * CIN_ + wq * 8);

    // compute helper indices
    #define COMPUTE_TG(TG, WB)                                                  \
    {                                                                           \
        _Pragma("unroll")                                                       \
        for (int t = 0; t < 3; ++t) {                                           \
            bf16x8 av[4];                                                       \
            _Pragma("unroll")                                                   \
            for (int mf = 0; mf < 4; ++mf) {                                    \
                int col = mf * 16 + lm;                                         \
                int unit = t * 256 + col * 4 + (hi ^ ((col >> 1) & 3));         \
                av[mf] = *(const bf16x8*)&lwt[WB][(size_t)unit * 8];            \
            }                                                                   \
            _Pragma("unroll")                                                   \
            for (int r = 0; r < 8; ++r) {                                       \
                int c = wv * 16 + lm + t;                                       \
                int rc = (r + (TG)) * 66 + c;                                   \
                int unit = rc * 4 + (hi ^ ((c >> 1) & 3));                      \
                bf16x8 bv = *(const bf16x8*)&lin[(size_t)unit * 8];             \
                _Pragma("unroll")                                               \
                for (int mf = 0; mf < 4; ++mf)                                  \
                    acc[mf][r] = __builtin_amdgcn_mfma_f32_16x16x32_bf16(       \
                        av[mf], bv, acc[mf][r], 0, 0, 0);                       \
            }                                                                   \
        }                                                                       \
    }

#pragma unroll 1
    for (int ch = 0; ch < 4; ++ch) {
        const int ci0 = ch * 32;
        __syncthreads();               // WAR: prior reads of lin / lwt[0] done
        // stage input halo 10x66 (2640 units = 10x256 + 80) + weights tg0
#pragma unroll
        for (int rd = 0; rd < 10; ++rd) {
            int o = rd * 256 + tid;
            int rc = o >> 2;
            int r = rc / 66, c = rc - 66 * r;
            int q = (o & 3) ^ ((c >> 1) & 3);
            GLOAD_LDS16(xb + (size_t)((R0 + r) * PW_ + (C0 + c)) * CIN_ + ci0 + q * 8,
                        &lin[(size_t)(rd * 256 + wv * 64) * 8]);
        }
        if (tid < 80) {
            int o = 2560 + tid;
            int rc = o >> 2;
            int r = rc / 66, c = rc - 66 * r;
            int q = (o & 3) ^ ((c >> 1) & 3);
            GLOAD_LDS16(xb + (size_t)((R0 + r) * PW_ + (C0 + c)) * CIN_ + ci0 + q * 8,
                        &lin[(size_t)(2560 + wv * 64) * 8]);
        }
#pragma unroll
        for (int rd = 0; rd < 3; ++rd)
            GLOAD_LDS16(wT + (size_t)rd * CIN_ * CIN_ + soffW + ci0,
                        &lwt[0][(size_t)(rd * 256 + wv * 64) * 8]);
        __syncthreads();               // input + w0 ready

        // tg0: prefetch w1 -> lwt[1]; compute taps 0-2 from lwt[0]
#pragma unroll
        for (int rd = 0; rd < 3; ++rd)
            GLOAD_LDS16(wT + (size_t)(3 + rd) * CIN_ * CIN_ + soffW + ci0,
                        &lwt[1][(size_t)(rd * 256 + wv * 64) * 8]);
        COMPUTE_TG(0, 0);
        __syncthreads();               // w1 ready; lwt[0] readers done

        // tg1: prefetch w2 -> lwt[0]; compute from lwt[1]
#pragma unroll
        for (int rd = 0; rd < 3; ++rd)
            GLOAD_LDS16(wT + (size_t)(6 + rd) * CIN_ * CIN_ + soffW + ci0,
                        &lwt[0][(size_t)(rd * 256 + wv * 64) * 8]);
        COMPUTE_TG(1, 1);
        __syncthreads();               // w2 ready

        // tg2: compute from lwt[0]
        COMPUTE_TG(2, 0);
    }
    #undef COMPUTE_TG

    // epilogue: BN + ReLU, pack 4 co bf16 per lane, 8B store
#pragma unroll
    for (int mf = 0; mf < 4; ++mf) {
        int co0 = cob + mf * 16 + hi * 4;
        float4 g4 = *(const float4*)(gg + co0);
        float4 b4 = *(const float4*)(bbn + co0);
        float4 m4 = *(const float4*)(mmn + co0);
        float4 v4 = *(const float4*)(vvn + co0);
        float sc0 = g4.x / sqrtf(v4.x + 1e-5f), sh0 = b4.x - m4.x * sc0;
        float sc1 = g4.y / sqrtf(v4.y + 1e-5f), sh1 = b4.y - m4.y * sc1;
        float sc2 = g4.z / sqrtf(v4.z + 1e-5f), sh2 = b4.z - m4.z * sc2;
        float sc3 = g4.w / sqrtf(v4.w + 1e-5f), sh3 = b4.w - m4.w * sc3;
#pragma unroll
        for (int r = 0; r < 8; ++r) {
            f32x4 A = acc[mf][r];
            float y0 = fmaxf(fmaf(A[0], sc0, sh0), 0.f);
            float y1 = fmaxf(fmaf(A[1], sc1, sh1), 0.f);
            float y2 = fmaxf(fmaf(A[2], sc2, sh2), 0.f);
            float y3 = fmaxf(fmaf(A[3], sc3, sh3), 0.f);
            unsigned p0 = (unsigned)f2bf(y0) | ((unsigned)f2bf(y1) << 16);
            unsigned p1 = (unsigned)f2bf(y2) | ((unsigned)f2bf(y3) << 16);
            u16* op = yT + (size_t)b * PW_ * PW_ * CIN_ +
                      ((size_t)(R0 + r + 1) * PW_ + (C0 + wv * 16 + lm + 1)) * CIN_ + co0;
            *(uint2*)op = make_uint2(p0, p1);
        }
    }
}

// ---------------------------------------------------------------------------
// head: 2 hm + 9 reg (co padded to 16), round-5 structure (validated) +
// fused heatmap_mask epilogue (objects runs BEFORE convs).
// ---------------------------------------------------------------------------
__global__ __launch_bounds__(256) void k_head_v9(
    const u16* __restrict__ f2T, const u16* __restrict__ wTh,
    const float* __restrict__ hb, const float* __restrict__ rb,
    float* __restrict__ out)
{
    __shared__ u16 lin[1600 * 8];
    __shared__ u16 lwt[2304 * 8];        // [tap][co16][16 ci-units swz]

    int tid  = threadIdx.x;
    int wv   = tid >> 6, lane = tid & 63;
    int lm   = lane & 15, hi = lane >> 4;
    int csp  = blockIdx.x;
    int C0   = (csp == 2) ? 116 : csp * 64;
    int R0   = blockIdx.y * 4;
    int b    = blockIdx.z;
    const u16* xb = f2T + (size_t)b * PW_ * PW_ * CIN_;

    f32x4 acc[4];
#pragma unroll
    for (int i = 0; i < 4; ++i) acc[i] = (f32x4){0.f, 0.f, 0.f, 0.f};

    // stage all head weights once: 2304 units, 9 rounds
#pragma unroll
    for (int rd = 0; rd < 9; ++rd) {
        int o = rd * 256 + tid;
        int tap = o >> 8, rest = o & 255;
        int co = rest >> 4, u8s = rest & 15;
        const u16* src = wTh + (size_t)tap * 16 * CIN_ + co * CIN_ + ((u8s ^ (co & 7)) * 8);
        GLOAD_LDS16(src, &lwt[(size_t)(rd * 256 + wv * 64) * 8]);
    }

#pragma unroll 1
    for (int ch = 0; ch < 4; ++ch) {
        int ci0 = ch * 32;
        __syncthreads();
#pragma unroll
        for (int rd = 0; rd < 6; ++rd) {
            int o = rd * 256 + tid;
            int rc = o >> 2;
            int r = rc / 66, c = rc - 66 * r;
            int q = (o & 3) ^ ((c >> 1) & 3);
            const u16* src = xb + ((size_t)(R0 + r) * PW_ + (C0 + c)) * CIN_ + ci0 + q * 8;
            GLOAD_LDS16(src, &lin[(size_t)(rd * 256 + wv * 64) * 8]);
        }
        if (tid < 64) {
            int o = 1536 + tid;
            int rc = o >> 2;
            int r = rc / 66, c = rc - 66 * r;
            if (o >= 1584) { r = 5; c = 65; }
            int q = (o & 3) ^ ((c >> 1) & 3);
            const u16* src = xb + ((size_t)(R0 + r) * PW_ + (C0 + c)) * CIN_ + ci0 + q * 8;
            GLOAD_LDS16(src, &lin[(size_t)1536 * 8]);
        }
        __syncthreads();

#pragma unroll
        for (int tap = 0; tap < 9; ++tap) {
            const int kr = tap / 3, kc = tap - 3 * (tap / 3);
            int u8 = (ch * 4 + hi) ^ (lm & 7);
            bf16x8 av = *(const bf16x8*)&lwt[(size_t)(tap * 256 + lm * 16 + u8) * 8];
#pragma unroll
            for (int nf = 0; nf < 4; ++nf) {
                int c = wv * 16 + lm + kc;
                int rc = (nf + kr) * 66 + c;
                int unit = rc * 4 + (hi ^ ((c >> 1) & 3));
                bf16x8 bv = *(const bf16x8*)&lin[(size_t)unit * 8];
                acc[nf] = __builtin_amdgcn_mfma_f32_16x16x32_bf16(av, bv, acc[nf], 0, 0, 0);
            }
        }
    }

#pragma unroll
    for (int nf = 0; nf < 4; ++nf) {
        int row = R0 + nf, col = C0 + wv * 16 + lm;
        f32x4 A = acc[nf];
#pragma unroll
        for (int r = 0; r < 4; ++r) {
            int co = hi * 4 + r;
            float v = A[r];
            if (co < 2)
                out[HM_OFF + ((size_t)(b * 2 + co)) * HW_ + (size_t)row * FW_ + col] = v + hb[co];
            else if (co < 11)
                out[REG_OFF + ((size_t)(b * 9 + co - 2)) * HW_ + (size_t)row * FW_ + col] = v + rb[co - 2];
        }
    }

    // fused heatmap_mask: 540 blocks x 480 elems = 259200 exactly
    int blk = (b * 45 + (int)blockIdx.y) * 3 + csp;
    int base = blk * 480;
    for (int i = base + tid; i < base + 480; i += 256) {
        float v = out[HEAT_OFF + i];
        out[HMM_OFF + i] = v > 0.f ? 1.f : 0.f;
    }
}

// ---------------------------------------------------------------------------
// targets (unchanged — validated rounds 1-11); launched BEFORE the convs
// ---------------------------------------------------------------------------
__global__ void k_objects(const float* __restrict__ gt, float* __restrict__ out)
{
    int ob = blockIdx.x;
    int b = ob / MM_, m = ob % MM_;
    const float* gp = gt + (size_t)ob * 8;
    float x = gp[0], y = gp[1], z = gp[2];
    float dx = gp[3], dy = gp[4], dz = gp[5], ry = gp[6];
    int cls = (int)gp[7];

    float coord_x = fminf(fmaxf((x + 54.f) / 0.075f / 8.f, 0.f), 179.5f);
    float coord_y = fminf(fmaxf((y + 54.f) / 0.075f / 8.f, 0.f), 179.5f);
    int cxi = (int)coord_x, cyi = (int)coord_y;
    float dxp = dx / 0.075f / 8.f;
    float dyp = dy / 0.075f / 8.f;

    float hgt = dxp, wid = dyp, mo = 0.1f;
    float b1 = hgt + wid, c1 = wid * hgt * (1.f - mo) / (1.f + mo);
    float r1 = (b1 + sqrtf(fmaxf(b1 * b1 - 4.f * c1, 0.f))) * 0.5f;
    float b2 = 2.f * (hgt + wid), c2 = (1.f - mo) * wid * hgt;
    float r2 = (b2 + sqrtf(fmaxf(b2 * b2 - 16.f * c2, 0.f))) * 0.5f;
    float a3 = 4.f * mo, b3 = -2.f * mo * (hgt + wid), c3 = (mo - 1.f) * wid * hgt;
    float r3 = (b3 + sqrtf(fmaxf(b3 * b3 - 4.f * a3 * c3, 0.f))) / (2.f * a3);
    int radius = max((int)fminf(fminf(r1, r2), r3), 2);

    bool valid = (dxp > 0.f) && (dyp > 0.f);
    bool pos = valid && (cls >= 1);

    if (threadIdx.x == 0) {
        float m0 = valid ? (cls >= 1 ? 1.f : -1.f) : 0.f;
        bool w_cond = (0.075f * 8.f) > dy / 4.f;
        bool l_cond = (0.075f * 8.f) > dx / 4.f;
        bool s1 = valid && !w_cond && (cxi - 1 >= 0);
        bool s2 = valid && !w_cond && (cxi + 1 < FW_);
        bool s3 = valid && !l_cond && (cyi - 1 >= 0);
        bool s4 = valid && !l_cond && (cyi + 1 < FH_);
        int base_ind = cyi * FW_ + cxi;

        float* indp = out + IND_OFF + (size_t)b * MM_ * 5 + m * 5;
        float* mskp = out + MSK_OFF + (size_t)b * MM_ * 5 + m * 5;
        indp[0] = valid ? (float)base_ind : 0.f;
        indp[1] = s1 ? (float)(base_ind - 1) : 0.f;
        indp[2] = s2 ? (float)(base_ind + 1) : 0.f;
        indp[3] = s3 ? (float)(base_ind - FW_) : 0.f;
        indp[4] = s4 ? (float)(base_ind + FW_) : 0.f;
        mskp[0] = m0;
        mskp[1] = s1 ? m0 : 0.f;
        mskp[2] = s2 ? m0 : 0.f;
        mskp[3] = s3 ? m0 : 0.f;
        mskp[4] = s4 ? m0 : 0.f;

        float offx = coord_x - (float)cxi;
        float offy = coord_y - (float)cyi;
        float bse[8] = { offx, offy, z,
                         logf(fmaxf(dx, 1e-8f)), logf(fmaxf(dy, 1e-8f)),
                         logf(fmaxf(dz, 1e-8f)), cosf(ry), sinf(ry) };
        float vm = valid ? 1.f : 0.f;
        float* rbp = out + RB_OFF + ((size_t)b * MM_ + m) * 5 * 8;
#pragma unroll
        for (int s = 0; s < 5; ++s) {
            float t0 = bse[0], t1 = bse[1];
            if (s == 1) t0 += s1 ? 1.f : 0.f;
            if (s == 2) t0 -= s2 ? 1.f : 0.f;
            if (s == 3) t1 += s3 ? 1.f : 0.f;
            if (s == 4) t1 -= s4 ? 1.f : 0.f;
            rbp[s * 8 + 0] = t0 * vm;
            rbp[s * 8 + 1] = t1 * vm;
#pragma unroll
            for (int k = 2; k < 8; ++k) rbp[s * 8 + k] = bse[k] * vm;
        }
    }

    if (pos) {
        float sigma = (2.f * (float)radius + 1.f) / 6.f;
        float inv2s2 = 1.f / (2.f * sigma * sigma);
        int x0 = max(cxi - radius, 0), x1 = min(cxi + radius, FW_ - 1);
        int y0 = max(cyi - radius, 0), y1 = min(cyi + radius, FH_ - 1);
        int wdt = x1 - x0 + 1, tot = wdt * (y1 - y0 + 1);
        float* hp = out + HEAT_OFF + (size_t)(b * 2 + (cls - 1)) * HW_;
        for (int i = threadIdx.x; i < tot; i += blockDim.x) {
            int yy = y0 + i / wdt, xx = x0 + i % wdt;
            float ddy = (float)(yy - cyi), ddx = (float)(xx - cxi);
            float gvl = expf(-(ddy * ddy + ddx * ddx) * inv2s2);
            atomicMax((int*)(hp + yy * FW_ + xx), __float_as_int(gvl));
        }
    }
}

// ---------------------------------------------------------------------------
extern "C" void kernel_launch(void* const* d_in, const int* in_sizes, int n_in,
                              void* d_out, int out_size, void* d_ws, size_t ws_size,
                              hipStream_t stream)
{
    const float* x  = (const float*)d_in[0];
    const float* gt = (const float*)d_in[1];
    const float* w1 = (const float*)d_in[2];
    const float* g1 = (const float*)d_in[3];
    const float* b1 = (const float*)d_in[4];
    const float* m1 = (const float*)d_in[5];
    const float* v1 = (const float*)d_in[6];
    const float* w2 = (const float*)d_in[7];
    const float* g2 = (const float*)d_in[8];
    const float* b2 = (const float*)d_in[9];
    const float* m2 = (const float*)d_in[10];
    const float* v2 = (const float*)d_in[11];
    const float* hw = (const float*)d_in[12];
    const float* hb = (const float*)d_in[13];
    const float* rw = (const float*)d_in[14];
    const float* rb = (const float*)d_in[15];
    float* out = (float*)d_out;

    u16* ws  = (u16*)d_ws;
    u16* xT  = ws;
    u16* f1T = ws + PADE;
    u16* f2T = ws + 2 * PADE;
    u16* wT1 = ws + 3 * PADE;
    u16* wT2 = wT1 + 9 * CIN_ * CIN_;
    u16* wTh = wT2 + 9 * CIN_ * CIN_;

    const int NTOT = 3 * BB_ * PW_ * PW_ + BB_ * 2 * HW_
                   + 2 * 9 * CIN_ * CIN_ + 9 * 16 * CIN_;
    k_init_w<<<(NTOT + 255) / 256, 256, 0, stream>>>(ws, out, w1, w2, hw, rw,
                                                     wT1, wT2, wTh);
    k_prep_xT<<<dim3(180, BB_), 256, 0, stream>>>(x, xT);
    k_objects<<<BB_ * MM_, 64, 0, stream>>>(gt, out);

    k_conv_v12<<<552, 256, 0, stream>>>(xT,  wT1, g1, b1, m1, v1, f1T);
    k_conv_v12<<<552, 256, 0, stream>>>(f1T, wT2, g2, b2, m2, v2, f2T);

    dim3 hg(3, 45, BB_);
    k_head_v9<<<hg, 256, 0, stream>>>(f2T, wTh, hb, rb, out);
}

// Round 13
// 147.152 us; speedup vs baseline: 1.0883x; 1.0883x over previous
//
#include <hip/hip_runtime.h>
#include <math.h>

typedef unsigned short u16;
typedef short bf16x8 __attribute__((ext_vector_type(8)));
typedef float f32x4 __attribute__((ext_vector_type(4)));

#define FW_ 180
#define FH_ 180
#define HW_ (FW_*FH_)
#define CIN_ 128
#define BB_ 4
#define MM_ 500
#define PW_ 182
#define PADE ((size_t)BB_*PW_*PW_*CIN_)

// d_out segment offsets (floats), in reference return order
#define HM_OFF   0
#define REG_OFF  (BB_*2*HW_)
#define HEAT_OFF (REG_OFF + BB_*9*HW_)
#define RB_OFF   (HEAT_OFF + BB_*2*HW_)
#define IND_OFF  (RB_OFF + BB_*MM_*5*8)
#define MSK_OFF  (IND_OFF + BB_*MM_*5)
#define HMM_OFF  (MSK_OFF + BB_*MM_*5)

__device__ inline u16 f2bf(float f) {
    unsigned u = __float_as_uint(f);
    u += 0x7FFFu + ((u >> 16) & 1u);           // RNE
    return (u16)(u >> 16);
}

#define GLOAD_LDS16(gsrc, ldst) \
    __builtin_amdgcn_global_load_lds( \
        (const __attribute__((address_space(1))) unsigned*)(gsrc), \
        (__attribute__((address_space(3))) unsigned*)(ldst), 16, 0, 0)

// ---------------------------------------------------------------------------
// merged init: zero padded-buffer borders + zero heatmap + weight transposes
// ---------------------------------------------------------------------------
__global__ void k_init_w(u16* __restrict__ ws, float* __restrict__ out,
                         const float* __restrict__ w1, const float* __restrict__ w2,
                         const float* __restrict__ hw, const float* __restrict__ rw,
                         u16* __restrict__ wT1, u16* __restrict__ wT2,
                         u16* __restrict__ wTh)
{
    int idx = blockIdx.x * 256 + threadIdx.x;
    const int n1 = 3 * BB_ * PW_ * PW_;
    const int n2 = n1 + BB_ * 2 * HW_;
    const int NW = 9 * CIN_ * CIN_;
    const int n3 = n2 + NW;
    const int n4 = n3 + NW;
    const int n5 = n4 + 9 * 16 * CIN_;
    if (idx < n1) {
        int buf = idx / (BB_ * PW_ * PW_);
        int rem = idx % (BB_ * PW_ * PW_);
        int p = rem % (PW_ * PW_);
        int r = p / PW_, c = p % PW_;
        if (r > 0 && r < PW_ - 1 && c > 0 && c < PW_ - 1) return;
        u16* base = ws + (size_t)buf * PADE + (size_t)rem * CIN_;
#pragma unroll
        for (int i = 0; i < 16; ++i) ((uint4*)base)[i] = make_uint4(0, 0, 0, 0);
    } else if (idx < n2) {
        out[HEAT_OFF + (idx - n1)] = 0.f;
    } else if (idx < n3) {
        int j = idx - n2;
        int tap = j / (CIN_ * CIN_);
        int r = j % (CIN_ * CIN_);
        int co = r >> 7, ci = r & 127;
        wT1[j] = f2bf(w1[((size_t)co * CIN_ + ci) * 9 + tap]);
    } else if (idx < n4) {
        int j = idx - n3;
        int tap = j / (CIN_ * CIN_);
        int r = j % (CIN_ * CIN_);
        int co = r >> 7, ci = r & 127;
        wT2[j] = f2bf(w2[((size_t)co * CIN_ + ci) * 9 + tap]);
    } else if (idx < n5) {
        int j = idx - n4;
        int tap = j / (16 * CIN_);
        int r = j % (16 * CIN_);
        int co = r >> 7, ci = r & 127;
        float v = 0.f;
        if (co < 2)       v = hw[((size_t)co * CIN_ + ci) * 9 + tap];
        else if (co < 11) v = rw[((size_t)(co - 2) * CIN_ + ci) * 9 + tap];
        wTh[j] = f2bf(v);
    }
}

// ---------------------------------------------------------------------------
// x (f32 NCHW) -> xT (bf16 [b][row+1][col+1][ci] padded); 16B stores
// ---------------------------------------------------------------------------
__global__ __launch_bounds__(256) void k_prep_xT(const float* __restrict__ in,
                                                 u16* __restrict__ xT)
{
    __shared__ unsigned lt32[180 * 65];        // [col][ci2] packed 2xbf16
    int tid = threadIdx.x;
    int row = blockIdx.x, b = blockIdx.y;
    const float* inr = in + ((size_t)b * CIN_ * FH_ + row) * FW_;
    for (int i = tid; i < 64 * 45; i += 256) {
        int ci2 = i / 45, c4 = i - 45 * ci2;
        const float* p0 = inr + (size_t)(2 * ci2) * HW_ + c4 * 4;
        float4 a = *(const float4*)p0;
        float4 bq = *(const float4*)(p0 + HW_);
        lt32[(c4 * 4 + 0) * 65 + ci2] = (unsigned)f2bf(a.x) | ((unsigned)f2bf(bq.x) << 16);
        lt32[(c4 * 4 + 1) * 65 + ci2] = (unsigned)f2bf(a.y) | ((unsigned)f2bf(bq.y) << 16);
        lt32[(c4 * 4 + 2) * 65 + ci2] = (unsigned)f2bf(a.z) | ((unsigned)f2bf(bq.z) << 16);
        lt32[(c4 * 4 + 3) * 65 + ci2] = (unsigned)f2bf(a.w) | ((unsigned)f2bf(bq.w) << 16);
    }
    __syncthreads();
    unsigned* dst = (unsigned*)(xT + ((size_t)b * PW_ * PW_ + (size_t)(row + 1) * PW_ + 1) * CIN_);
    for (int idx = tid; idx < 180 * 16; idx += 256) {
        int col = idx >> 4, q = idx & 15;
        uint4 v;
        v.x = lt32[col * 65 + q * 4 + 0];
        v.y = lt32[col * 65 + q * 4 + 1];
        v.z = lt32[col * 65 + q * 4 + 2];
        v.w = lt32[col * 65 + q * 4 + 3];
        *(uint4*)&dst[col * 64 + q * 4] = v;
    }
}

// ---------------------------------------------------------------------------
// conv 3x3 SAME 128->128 + BN + ReLU.  v10 tile + T4 counted-vmcnt schedule.
// Phase p = (ch,tg): compute 3 taps from lwt[tg] & lin. Weights for phase
// p+1 are issued into lwt[(tg+1)%3] BEFORE a counted s_waitcnt vmcnt(3) --
// the barrier never drains the staging queue (m233/m218 lever). Triple
// buffering makes the WAR legal: lwt[tg']'s last readers ran two phases
// back, fenced by the intervening barrier. Input single-buffered, drained
// only at the 4 chunk boundaries (2-barrier there, 1-barrier otherwise).
// In-flight ledger at each waitcnt: [w(p)=3, (input 3|4), w(p+1)=3] ->
// vmcnt(3) retires all but w(p+1), uniformly across waves.
// LDS 25.6 + 3x12.3 = 62.5 KB -> 2 blocks/CU. Grid 1080 = 8x135 XCD-swz.
// ---------------------------------------------------------------------------
__global__ __launch_bounds__(256, 2) void k_conv_v13(
    const u16* __restrict__ xT, const u16* __restrict__ wT,
    const float* __restrict__ gg, const float* __restrict__ bbn,
    const float* __restrict__ mmn, const float* __restrict__ vvn,
    u16* __restrict__ yT)
{
    __shared__ u16 lin[1600 * 8];        // 25.6 KB input halo chunk
    __shared__ u16 lwt[3][768 * 8];      // 3 x 12.3 KB: 3 taps x 64co x 32ci

    int tid  = threadIdx.x;
    int wv   = tid >> 6, lane = tid & 63;
    int lm   = lane & 15, hi = lane >> 4;

    // XCD swizzle: 1080 blocks = 8 XCDs x 135 (bijective)
    int wg   = blockIdx.x;
    int wgid = (wg & 7) * 135 + (wg >> 3);
    int b    = wgid / 270;
    int rem  = wgid % 270;
    int row  = rem / 6;
    int t6   = rem % 6;
    int csp  = t6 % 3, cog = t6 / 3;
    int C0   = (csp == 2) ? 116 : csp * 64;
    int cob  = cog * 64;
    int R0   = row * 4;
    const u16* xb = xT + (size_t)b * PW_ * PW_ * CIN_;

    f32x4 acc[4][4];
#pragma unroll
    for (int i = 0; i < 4; ++i)
#pragma unroll
        for (int j = 0; j < 4; ++j) acc[i][j] = (f32x4){0.f, 0.f, 0.f, 0.f};

    // input staging source offsets (validated scheme)
    unsigned soffI[6];
#pragma unroll
    for (int rd = 0; rd < 6; ++rd) {
        int o = rd * 256 + tid;
        int rc = o >> 2;
        int r = rc / 66, c = rc - 66 * r;
        int q = (o & 3) ^ ((c >> 1) & 3);
        soffI[rd] = (unsigned)(((R0 + r) * PW_ + (C0 + c)) * CIN_ + q * 8);
    }
    unsigned soffX = 0;
    if (tid < 64) {
        int o = 1536 + tid;
        int rc = o >> 2;
        int r = rc / 66, c = rc - 66 * r;
        if (o >= 1584) { r = 5; c = 65; }
        int q = (o & 3) ^ ((c >> 1) & 3);
        soffX = (unsigned)(((R0 + r) * PW_ + (C0 + c)) * CIN_ + q * 8);
    }
    // weight staging source offset (one tap per round)
    const int wco = tid >> 2;
    const int wq  = (tid & 3) ^ ((wco >> 1) & 3);
    const unsigned soffW = (unsigned)((cob + wco) * CIN_ + wq * 8);

    #define STAGE_IN(CH)                                                        \
    {                                                                           \
        _Pragma("unroll")                                                       \
        for (int rd = 0; rd < 6; ++rd)                                          \
            GLOAD_LDS16(xb + soffI[rd] + (CH) * 32,                             \
                        &lin[(size_t)(rd * 256 + wv * 64) * 8]);                \
        if (tid < 64)                                                           \
            GLOAD_LDS16(xb + soffX + (CH) * 32, &lin[(size_t)1536 * 8]);        \
    }
    #define STAGE_W(NCH, NTG)                                                   \
    {                                                                           \
        _Pragma("unroll")                                                       \
        for (int rd = 0; rd < 3; ++rd)                                          \
            GLOAD_LDS16(wT + (size_t)((NTG) * 3 + rd) * CIN_ * CIN_ + soffW + (NCH) * 32, \
                        &lwt[NTG][(size_t)(rd * 256 + wv * 64) * 8]);           \
    }
    #define COMPUTE_TG(TG)                                                      \
    {                                                                           \
        _Pragma("unroll")                                                       \
        for (int t = 0; t < 3; ++t) {                                           \
            bf16x8 av[4];                                                       \
            _Pragma("unroll")                                                   \
            for (int mf = 0; mf < 4; ++mf) {                                    \
                int col = mf * 16 + lm;                                         \
                int unit = t * 256 + col * 4 + (hi ^ ((col >> 1) & 3));         \
                av[mf] = *(const bf16x8*)&lwt[TG][(size_t)unit * 8];            \
            }                                                                   \
            _Pragma("unroll")                                                   \
            for (int nf = 0; nf < 4; ++nf) {                                    \
                int c = wv * 16 + lm + t;                                       \
                int rc = (nf + (TG)) * 66 + c;                                  \
                int unit = rc * 4 + (hi ^ ((c >> 1) & 3));                      \
                bf16x8 bv = *(const bf16x8*)&lin[(size_t)unit * 8];             \
                _Pragma("unroll")                                               \
                for (int mf = 0; mf < 4; ++mf)                                  \
                    acc[mf][nf] = __builtin_amdgcn_mfma_f32_16x16x32_bf16(      \
                        av[mf], bv, acc[mf][nf], 0, 0, 0);                      \
            }                                                                   \
        }                                                                       \
    }

    // prologue: stage input(0) + weights(ch0, tg0)
    STAGE_IN(0);
    STAGE_W(0, 0);

#pragma unroll
    for (int ch = 0; ch < 4; ++ch) {
#pragma unroll
        for (int tg = 0; tg < 3; ++tg) {
            if (tg == 0 && ch > 0) {
                // barrier A: all compute(prev phase) done -> lin free
                __builtin_amdgcn_s_barrier();
                __builtin_amdgcn_sched_barrier(0);
                STAGE_IN(ch);
            }
            const bool last = (ch == 3 && tg == 2);
            if (!last) {
                const int nch = (tg == 2) ? ch + 1 : ch;
                const int ntg = (tg + 1) % 3;
                STAGE_W(nch, ntg);
                asm volatile("s_waitcnt vmcnt(3)" ::: "memory");
            } else {
                asm volatile("s_waitcnt vmcnt(0)" ::: "memory");
            }
            __builtin_amdgcn_s_barrier();
            __builtin_amdgcn_sched_barrier(0);
            COMPUTE_TG(tg);
        }
    }
    #undef STAGE_IN
    #undef STAGE_W
    #undef COMPUTE_TG

    // epilogue: BN + ReLU, pack 4 co bf16 per lane, 8B store
#pragma unroll
    for (int mf = 0; mf < 4; ++mf) {
        int co0 = cob + mf * 16 + hi * 4;
        float4 g4 = *(const float4*)(gg + co0);
        float4 b4 = *(const float4*)(bbn + co0);
        float4 m4 = *(const float4*)(mmn + co0);
        float4 v4 = *(const float4*)(vvn + co0);
        float sc0 = g4.x / sqrtf(v4.x + 1e-5f), sh0 = b4.x - m4.x * sc0;
        float sc1 = g4.y / sqrtf(v4.y + 1e-5f), sh1 = b4.y - m4.y * sc1;
        float sc2 = g4.z / sqrtf(v4.z + 1e-5f), sh2 = b4.z - m4.z * sc2;
        float sc3 = g4.w / sqrtf(v4.w + 1e-5f), sh3 = b4.w - m4.w * sc3;
#pragma unroll
        for (int nf = 0; nf < 4; ++nf) {
            f32x4 A = acc[mf][nf];
            float y0 = fmaxf(fmaf(A[0], sc0, sh0), 0.f);
            float y1 = fmaxf(fmaf(A[1], sc1, sh1), 0.f);
            float y2 = fmaxf(fmaf(A[2], sc2, sh2), 0.f);
            float y3 = fmaxf(fmaf(A[3], sc3, sh3), 0.f);
            unsigned p0 = (unsigned)f2bf(y0) | ((unsigned)f2bf(y1) << 16);
            unsigned p1 = (unsigned)f2bf(y2) | ((unsigned)f2bf(y3) << 16);
            u16* op = yT + (size_t)b * PW_ * PW_ * CIN_ +
                      ((size_t)(R0 + nf + 1) * PW_ + (C0 + wv * 16 + lm + 1)) * CIN_ + co0;
            *(uint2*)op = make_uint2(p0, p1);
        }
    }
}

// ---------------------------------------------------------------------------
// head: 2 hm + 9 reg (co padded to 16), round-5 structure (validated) +
// fused heatmap_mask epilogue (objects runs BEFORE convs).
// ---------------------------------------------------------------------------
__global__ __launch_bounds__(256) void k_head_v9(
    const u16* __restrict__ f2T, const u16* __restrict__ wTh,
    const float* __restrict__ hb, const float* __restrict__ rb,
    float* __restrict__ out)
{
    __shared__ u16 lin[1600 * 8];
    __shared__ u16 lwt[2304 * 8];        // [tap][co16][16 ci-units swz]

    int tid  = threadIdx.x;
    int wv   = tid >> 6, lane = tid & 63;
    int lm   = lane & 15, hi = lane >> 4;
    int csp  = blockIdx.x;
    int C0   = (csp == 2) ? 116 : csp * 64;
    int R0   = blockIdx.y * 4;
    int b    = blockIdx.z;
    const u16* xb = f2T + (size_t)b * PW_ * PW_ * CIN_;

    f32x4 acc[4];
#pragma unroll
    for (int i = 0; i < 4; ++i) acc[i] = (f32x4){0.f, 0.f, 0.f, 0.f};

    // stage all head weights once: 2304 units, 9 rounds
#pragma unroll
    for (int rd = 0; rd < 9; ++rd) {
        int o = rd * 256 + tid;
        int tap = o >> 8, rest = o & 255;
        int co = rest >> 4, u8s = rest & 15;
        const u16* src = wTh + (size_t)tap * 16 * CIN_ + co * CIN_ + ((u8s ^ (co & 7)) * 8);
        GLOAD_LDS16(src, &lwt[(size_t)(rd * 256 + wv * 64) * 8]);
    }

#pragma unroll 1
    for (int ch = 0; ch < 4; ++ch) {
        int ci0 = ch * 32;
        __syncthreads();
#pragma unroll
        for (int rd = 0; rd < 6; ++rd) {
            int o = rd * 256 + tid;
            int rc = o >> 2;
            int r = rc / 66, c = rc - 66 * r;
            int q = (o & 3) ^ ((c >> 1) & 3);
            const u16* src = xb + ((size_t)(R0 + r) * PW_ + (C0 + c)) * CIN_ + ci0 + q * 8;
            GLOAD_LDS16(src, &lin[(size_t)(rd * 256 + wv * 64) * 8]);
        }
        if (tid < 64) {
            int o = 1536 + tid;
            int rc = o >> 2;
            int r = rc / 66, c = rc - 66 * r;
            if (o >= 1584) { r = 5; c = 65; }
            int q = (o & 3) ^ ((c >> 1) & 3);
            const u16* src = xb + ((size_t)(R0 + r) * PW_ + (C0 + c)) * CIN_ + ci0 + q * 8;
            GLOAD_LDS16(src, &lin[(size_t)1536 * 8]);
        }
        __syncthreads();

#pragma unroll
        for (int tap = 0; tap < 9; ++tap) {
            const int kr = tap / 3, kc = tap - 3 * (tap / 3);
            int u8 = (ch * 4 + hi) ^ (lm & 7);
            bf16x8 av = *(const bf16x8*)&lwt[(size_t)(tap * 256 + lm * 16 + u8) * 8];
#pragma unroll
            for (int nf = 0; nf < 4; ++nf) {
                int c = wv * 16 + lm + kc;
                int rc = (nf + kr) * 66 + c;
                int unit = rc * 4 + (hi ^ ((c >> 1) & 3));
                bf16x8 bv = *(const bf16x8*)&lin[(size_t)unit * 8];
                acc[nf] = __builtin_amdgcn_mfma_f32_16x16x32_bf16(av, bv, acc[nf], 0, 0, 0);
            }
        }
    }

#pragma unroll
    for (int nf = 0; nf < 4; ++nf) {
        int row = R0 + nf, col = C0 + wv * 16 + lm;
        f32x4 A = acc[nf];
#pragma unroll
        for (int r = 0; r < 4; ++r) {
            int co = hi * 4 + r;
            float v = A[r];
            if (co < 2)
                out[HM_OFF + ((size_t)(b * 2 + co)) * HW_ + (size_t)row * FW_ + col] = v + hb[co];
            else if (co < 11)
                out[REG_OFF + ((size_t)(b * 9 + co - 2)) * HW_ + (size_t)row * FW_ + col] = v + rb[co - 2];
        }
    }

    // fused heatmap_mask: 540 blocks x 480 elems = 259200 exactly
    int blk = (b * 45 + (int)blockIdx.y) * 3 + csp;
    int base = blk * 480;
    for (int i = base + tid; i < base + 480; i += 256) {
        float v = out[HEAT_OFF + i];
        out[HMM_OFF + i] = v > 0.f ? 1.f : 0.f;
    }
}

// ---------------------------------------------------------------------------
// targets (unchanged — validated rounds 1-12); launched BEFORE the convs
// ---------------------------------------------------------------------------
__global__ void k_objects(const float* __restrict__ gt, float* __restrict__ out)
{
    int ob = blockIdx.x;
    int b = ob / MM_, m = ob % MM_;
    const float* gp = gt + (size_t)ob * 8;
    float x = gp[0], y = gp[1], z = gp[2];
    float dx = gp[3], dy = gp[4], dz = gp[5], ry = gp[6];
    int cls = (int)gp[7];

    float coord_x = fminf(fmaxf((x + 54.f) / 0.075f / 8.f, 0.f), 179.5f);
    float coord_y = fminf(fmaxf((y + 54.f) / 0.075f / 8.f, 0.f), 179.5f);
    int cxi = (int)coord_x, cyi = (int)coord_y;
    float dxp = dx / 0.075f / 8.f;
    float dyp = dy / 0.075f / 8.f;

    float hgt = dxp, wid = dyp, mo = 0.1f;
    float b1 = hgt + wid, c1 = wid * hgt * (1.f - mo) / (1.f + mo);
    float r1 = (b1 + sqrtf(fmaxf(b1 * b1 - 4.f * c1, 0.f))) * 0.5f;
    float b2 = 2.f * (hgt + wid), c2 = (1.f - mo) * wid * hgt;
    float r2 = (b2 + sqrtf(fmaxf(b2 * b2 - 16.f * c2, 0.f))) * 0.5f;
    float a3 = 4.f * mo, b3 = -2.f * mo * (hgt + wid), c3 = (mo - 1.f) * wid * hgt;
    float r3 = (b3 + sqrtf(fmaxf(b3 * b3 - 4.f * a3 * c3, 0.f))) / (2.f * a3);
    int radius = max((int)fminf(fminf(r1, r2), r3), 2);

    bool valid = (dxp > 0.f) && (dyp > 0.f);
    bool pos = valid && (cls >= 1);

    if (threadIdx.x == 0) {
        float m0 = valid ? (cls >= 1 ? 1.f : -1.f) : 0.f;
        bool w_cond = (0.075f * 8.f) > dy / 4.f;
        bool l_cond = (0.075f * 8.f) > dx / 4.f;
        bool s1 = valid && !w_cond && (cxi - 1 >= 0);
        bool s2 = valid && !w_cond && (cxi + 1 < FW_);
        bool s3 = valid && !l_cond && (cyi - 1 >= 0);
        bool s4 = valid && !l_cond && (cyi + 1 < FH_);
        int base_ind = cyi * FW_ + cxi;

        float* indp = out + IND_OFF + (size_t)b * MM_ * 5 + m * 5;
        float* mskp = out + MSK_OFF + (size_t)b * MM_ * 5 + m * 5;
        indp[0] = valid ? (float)base_ind : 0.f;
        indp[1] = s1 ? (float)(base_ind - 1) : 0.f;
        indp[2] = s2 ? (float)(base_ind + 1) : 0.f;
        indp[3] = s3 ? (float)(base_ind - FW_) : 0.f;
        indp[4] = s4 ? (float)(base_ind + FW_) : 0.f;
        mskp[0] = m0;
        mskp[1] = s1 ? m0 : 0.f;
        mskp[2] = s2 ? m0 : 0.f;
        mskp[3] = s3 ? m0 : 0.f;
        mskp[4] = s4 ? m0 : 0.f;

        float offx = coord_x - (float)cxi;
        float offy = coord_y - (float)cyi;
        float bse[8] = { offx, offy, z,
                         logf(fmaxf(dx, 1e-8f)), logf(fmaxf(dy, 1e-8f)),
                         logf(fmaxf(dz, 1e-8f)), cosf(ry), sinf(ry) };
        float vm = valid ? 1.f : 0.f;
        float* rbp = out + RB_OFF + ((size_t)b * MM_ + m) * 5 * 8;
#pragma unroll
        for (int s = 0; s < 5; ++s) {
            float t0 = bse[0], t1 = bse[1];
            if (s == 1) t0 += s1 ? 1.f : 0.f;
            if (s == 2) t0 -= s2 ? 1.f : 0.f;
            if (s == 3) t1 += s3 ? 1.f : 0.f;
            if (s == 4) t1 -= s4 ? 1.f : 0.f;
            rbp[s * 8 + 0] = t0 * vm;
            rbp[s * 8 + 1] = t1 * vm;
#pragma unroll
            for (int k = 2; k < 8; ++k) rbp[s * 8 + k] = bse[k] * vm;
        }
    }

    if (pos) {
        float sigma = (2.f * (float)radius + 1.f) / 6.f;
        float inv2s2 = 1.f / (2.f * sigma * sigma);
        int x0 = max(cxi - radius, 0), x1 = min(cxi + radius, FW_ - 1);
        int y0 = max(cyi - radius, 0), y1 = min(cyi + radius, FH_ - 1);
        int wdt = x1 - x0 + 1, tot = wdt * (y1 - y0 + 1);
        float* hp = out + HEAT_OFF + (size_t)(b * 2 + (cls - 1)) * HW_;
        for (int i = threadIdx.x; i < tot; i += blockDim.x) {
            int yy = y0 + i / wdt, xx = x0 + i % wdt;
            float ddy = (float)(yy - cyi), ddx = (float)(xx - cxi);
            float gvl = expf(-(ddy * ddy + ddx * ddx) * inv2s2);
            atomicMax((int*)(hp + yy * FW_ + xx), __float_as_int(gvl));
        }
    }
}

// ---------------------------------------------------------------------------
extern "C" void kernel_launch(void* const* d_in, const int* in_sizes, int n_in,
                              void* d_out, int out_size, void* d_ws, size_t ws_size,
                              hipStream_t stream)
{
    const float* x  = (const float*)d_in[0];
    const float* gt = (const float*)d_in[1];
    const float* w1 = (const float*)d_in[2];
    const float* g1 = (const float*)d_in[3];
    const float* b1 = (const float*)d_in[4];
    const float* m1 = (const float*)d_in[5];
    const float* v1 = (const float*)d_in[6];
    const float* w2 = (const float*)d_in[7];
    const float* g2 = (const float*)d_in[8];
    const float* b2 = (const float*)d_in[9];
    const float* m2 = (const float*)d_in[10];
    const float* v2 = (const float*)d_in[11];
    const float* hw = (const float*)d_in[12];
    const float* hb = (const float*)d_in[13];
    const float* rw = (const float*)d_in[14];
    const float* rb = (const float*)d_in[15];
    float* out = (float*)d_out;

    u16* ws  = (u16*)d_ws;
    u16* xT  = ws;
    u16* f1T = ws + PADE;
    u16* f2T = ws + 2 * PADE;
    u16* wT1 = ws + 3 * PADE;
    u16* wT2 = wT1 + 9 * CIN_ * CIN_;
    u16* wTh = wT2 + 9 * CIN_ * CIN_;

    const int NTOT = 3 * BB_ * PW_ * PW_ + BB_ * 2 * HW_
                   + 2 * 9 * CIN_ * CIN_ + 9 * 16 * CIN_;
    k_init_w<<<(NTOT + 255) / 256, 256, 0, stream>>>(ws, out, w1, w2, hw, rw,
                                                     wT1, wT2, wTh);
    k_prep_xT<<<dim3(180, BB_), 256, 0, stream>>>(x, xT);
    k_objects<<<BB_ * MM_, 64, 0, stream>>>(gt, out);

    k_conv_v13<<<1080, 256, 0, stream>>>(xT,  wT1, g1, b1, m1, v1, f1T);
    k_conv_v13<<<1080, 256, 0, stream>>>(f1T, wT2, g2, b2, m2, v2, f2T);

    dim3 hg(3, 45, BB_);
    k_head_v9<<<hg, 256, 0, stream>>>(f2T, wTh, hb, rb, out);
}

// Round 15
// 136.972 us; speedup vs baseline: 1.1692x; 1.0743x over previous
//
#include <hip/hip_runtime.h>
#include <math.h>

typedef unsigned short u16;
typedef short bf16x8 __attribute__((ext_vector_type(8)));
typedef float f32x4 __attribute__((ext_vector_type(4)));

#define FW_ 180
#define FH_ 180
#define HW_ (FW_*FH_)
#define CIN_ 128
#define BB_ 4
#define MM_ 500
#define PW_ 182
#define PADE ((size_t)BB_*PW_*PW_*CIN_)

// d_out segment offsets (floats), in reference return order
#define HM_OFF   0
#define REG_OFF  (BB_*2*HW_)
#define HEAT_OFF (REG_OFF + BB_*9*HW_)
#define RB_OFF   (HEAT_OFF + BB_*2*HW_)
#define IND_OFF  (RB_OFF + BB_*MM_*5*8)
#define MSK_OFF  (IND_OFF + BB_*MM_*5)
#define HMM_OFF  (MSK_OFF + BB_*MM_*5)

__device__ inline u16 f2bf(float f) {
    unsigned u = __float_as_uint(f);
    u += 0x7FFFu + ((u >> 16) & 1u);           // RNE
    return (u16)(u >> 16);
}

#define GLOAD_LDS16(gsrc, ldst) \
    __builtin_amdgcn_global_load_lds( \
        (const __attribute__((address_space(1))) unsigned*)(gsrc), \
        (__attribute__((address_space(3))) unsigned*)(ldst), 16, 0, 0)

// ---------------------------------------------------------------------------
// per-object target computation (one wave per object). Validated rounds 1-13.
// ---------------------------------------------------------------------------
__device__ void obj_work(int ob, int lane, const float* __restrict__ gt,
                         float* __restrict__ out)
{
    int b = ob / MM_, m = ob % MM_;
    const float* gp = gt + (size_t)ob * 8;
    float x = gp[0], y = gp[1], z = gp[2];
    float dx = gp[3], dy = gp[4], dz = gp[5], ry = gp[6];
    int cls = (int)gp[7];

    float coord_x = fminf(fmaxf((x + 54.f) / 0.075f / 8.f, 0.f), 179.5f);
    float coord_y = fminf(fmaxf((y + 54.f) / 0.075f / 8.f, 0.f), 179.5f);
    int cxi = (int)coord_x, cyi = (int)coord_y;
    float dxp = dx / 0.075f / 8.f;
    float dyp = dy / 0.075f / 8.f;

    float hgt = dxp, wid = dyp, mo = 0.1f;
    float b1 = hgt + wid, c1 = wid * hgt * (1.f - mo) / (1.f + mo);
    float r1 = (b1 + sqrtf(fmaxf(b1 * b1 - 4.f * c1, 0.f))) * 0.5f;
    float b2 = 2.f * (hgt + wid), c2 = (1.f - mo) * wid * hgt;
    float r2 = (b2 + sqrtf(fmaxf(b2 * b2 - 16.f * c2, 0.f))) * 0.5f;
    float a3 = 4.f * mo, b3 = -2.f * mo * (hgt + wid), c3 = (mo - 1.f) * wid * hgt;
    float r3 = (b3 + sqrtf(fmaxf(b3 * b3 - 4.f * a3 * c3, 0.f))) / (2.f * a3);
    int radius = max((int)fminf(fminf(r1, r2), r3), 2);

    bool valid = (dxp > 0.f) && (dyp > 0.f);
    bool pos = valid && (cls >= 1);

    if (lane == 0) {
        float m0 = valid ? (cls >= 1 ? 1.f : -1.f) : 0.f;
        bool w_cond = (0.075f * 8.f) > dy / 4.f;
        bool l_cond = (0.075f * 8.f) > dx / 4.f;
        bool s1 = valid && !w_cond && (cxi - 1 >= 0);
        bool s2 = valid && !w_cond && (cxi + 1 < FW_);
        bool s3 = valid && !l_cond && (cyi - 1 >= 0);
        bool s4 = valid && !l_cond && (cyi + 1 < FH_);
        int base_ind = cyi * FW_ + cxi;

        float* indp = out + IND_OFF + (size_t)b * MM_ * 5 + m * 5;
        float* mskp = out + MSK_OFF + (size_t)b * MM_ * 5 + m * 5;
        indp[0] = valid ? (float)base_ind : 0.f;
        indp[1] = s1 ? (float)(base_ind - 1) : 0.f;
        indp[2] = s2 ? (float)(base_ind + 1) : 0.f;
        indp[3] = s3 ? (float)(base_ind - FW_) : 0.f;
        indp[4] = s4 ? (float)(base_ind + FW_) : 0.f;
        mskp[0] = m0;
        mskp[1] = s1 ? m0 : 0.f;
        mskp[2] = s2 ? m0 : 0.f;
        mskp[3] = s3 ? m0 : 0.f;
        mskp[4] = s4 ? m0 : 0.f;

        float offx = coord_x - (float)cxi;
        float offy = coord_y - (float)cyi;
        float bse[8] = { offx, offy, z,
                         logf(fmaxf(dx, 1e-8f)), logf(fmaxf(dy, 1e-8f)),
                         logf(fmaxf(dz, 1e-8f)), cosf(ry), sinf(ry) };
        float vm = valid ? 1.f : 0.f;
        float* rbp = out + RB_OFF + ((size_t)b * MM_ + m) * 5 * 8;
#pragma unroll
        for (int s = 0; s < 5; ++s) {
            float t0 = bse[0], t1 = bse[1];
            if (s == 1) t0 += s1 ? 1.f : 0.f;
            if (s == 2) t0 -= s2 ? 1.f : 0.f;
            if (s == 3) t1 += s3 ? 1.f : 0.f;
            if (s == 4) t1 -= s4 ? 1.f : 0.f;
            rbp[s * 8 + 0] = t0 * vm;
            rbp[s * 8 + 1] = t1 * vm;
#pragma unroll
            for (int k = 2; k < 8; ++k) rbp[s * 8 + k] = bse[k] * vm;
        }
    }

    if (pos) {
        float sigma = (2.f * (float)radius + 1.f) / 6.f;
        float inv2s2 = 1.f / (2.f * sigma * sigma);
        int x0 = max(cxi - radius, 0), x1 = min(cxi + radius, FW_ - 1);
        int y0 = max(cyi - radius, 0), y1 = min(cyi + radius, FH_ - 1);
        int wdt = x1 - x0 + 1, tot = wdt * (y1 - y0 + 1);
        float* hp = out + HEAT_OFF + (size_t)(b * 2 + (cls - 1)) * HW_;
        for (int i = lane; i < tot; i += 64) {
            int yy = y0 + i / wdt, xx = x0 + i % wdt;
            float ddy = (float)(yy - cyi), ddx = (float)(xx - cxi);
            float gvl = expf(-(ddy * ddy + ddx * ddx) * inv2s2);
            atomicMax((int*)(hp + yy * FW_ + xx), __float_as_int(gvl));
        }
    }
}

// ---------------------------------------------------------------------------
// k_pre: fused pre-pass.
//  blocks [0,720): x (f32 NCHW) -> xT bf16 channel-last padded (per row).
//  blocks [720,..): flat: border zeros (perimeter decode), heat zero,
//  wT1/wT2/wTh transposes. All writes disjoint -> race-free.
// ---------------------------------------------------------------------------
__global__ __launch_bounds__(256) void k_pre(
    const float* __restrict__ x, u16* __restrict__ xT, u16* __restrict__ ws,
    float* __restrict__ out,
    const float* __restrict__ w1, const float* __restrict__ w2,
    const float* __restrict__ hw, const float* __restrict__ rw,
    u16* __restrict__ wT1, u16* __restrict__ wT2, u16* __restrict__ wTh)
{
    __shared__ unsigned lt32[180 * 65];
    int tid = threadIdx.x;
    if (blockIdx.x < 720) {
        int row = blockIdx.x % 180, b = blockIdx.x / 180;
        const float* inr = x + ((size_t)b * CIN_ * FH_ + row) * FW_;
        for (int i = tid; i < 64 * 45; i += 256) {
            int ci2 = i / 45, c4 = i - 45 * ci2;
            const float* p0 = inr + (size_t)(2 * ci2) * HW_ + c4 * 4;
            float4 a = *(const float4*)p0;
            float4 bq = *(const float4*)(p0 + HW_);
            lt32[(c4 * 4 + 0) * 65 + ci2] = (unsigned)f2bf(a.x) | ((unsigned)f2bf(bq.x) << 16);
            lt32[(c4 * 4 + 1) * 65 + ci2] = (unsigned)f2bf(a.y) | ((unsigned)f2bf(bq.y) << 16);
            lt32[(c4 * 4 + 2) * 65 + ci2] = (unsigned)f2bf(a.z) | ((unsigned)f2bf(bq.z) << 16);
            lt32[(c4 * 4 + 3) * 65 + ci2] = (unsigned)f2bf(a.w) | ((unsigned)f2bf(bq.w) << 16);
        }
        __syncthreads();
        unsigned* dst = (unsigned*)(xT + ((size_t)b * PW_ * PW_ + (size_t)(row + 1) * PW_ + 1) * CIN_);
        for (int idx = tid; idx < 180 * 16; idx += 256) {
            int col = idx >> 4, q = idx & 15;
            uint4 v;
            v.x = lt32[col * 65 + q * 4 + 0];
            v.y = lt32[col * 65 + q * 4 + 1];
            v.z = lt32[col * 65 + q * 4 + 2];
            v.w = lt32[col * 65 + q * 4 + 3];
            *(uint4*)&dst[col * 64 + q * 4] = v;
        }
        return;
    }

    int idx = (blockIdx.x - 720) * 256 + tid;
    if (idx < 12 * 724) {
        int which = idx / 724, cell = idx % 724;
        int buf = which >> 2, b = which & 3;
        int r, c;
        if (cell < 182)      { r = 0;   c = cell; }
        else if (cell < 364) { r = 181; c = cell - 182; }
        else { int s = cell - 364; r = 1 + (s >> 1); c = (s & 1) ? 181 : 0; }
        u16* base = ws + (size_t)buf * PADE + ((size_t)b * PW_ * PW_ + (size_t)r * PW_ + c) * CIN_;
#pragma unroll
        for (int i = 0; i < 16; ++i) ((uint4*)base)[i] = make_uint4(0, 0, 0, 0);
        return;
    }
    idx -= 12 * 724;
    if (idx < BB_ * 2 * HW_) { out[HEAT_OFF + idx] = 0.f; return; }
    idx -= BB_ * 2 * HW_;
    const int NW = 9 * CIN_ * CIN_;
    if (idx < NW) {
        int tap = idx / (CIN_ * CIN_);
        int r = idx % (CIN_ * CIN_);
        int co = r >> 7, ci = r & 127;
        wT1[idx] = f2bf(w1[((size_t)co * CIN_ + ci) * 9 + tap]);
        return;
    }
    idx -= NW;
    if (idx < NW) {
        int tap = idx / (CIN_ * CIN_);
        int r = idx % (CIN_ * CIN_);
        int co = r >> 7, ci = r & 127;
        wT2[idx] = f2bf(w2[((size_t)co * CIN_ + ci) * 9 + tap]);
        return;
    }
    idx -= NW;
    if (idx < 9 * 16 * CIN_) {
        int tap = idx / (16 * CIN_);
        int r = idx % (16 * CIN_);
        int co = r >> 7, ci = r & 127;
        float v = 0.f;
        if (co < 2)       v = hw[((size_t)co * CIN_ + ci) * 9 + tap];
        else if (co < 11) v = rw[((size_t)(co - 2) * CIN_ + ci) * 9 + tap];
        wTh[idx] = f2bf(v);
    }
}

// ---------------------------------------------------------------------------
// conv 3x3 SAME 128->128 + BN + ReLU.  v13 validated core (T4 counted
// vmcnt, triple-buffered weights). Blocks >= 1080 run the fused per-object
// target pass (conv1 only): 500 tail blocks x 4 waves = 2000 objects.
// ---------------------------------------------------------------------------
__global__ __launch_bounds__(256, 2) void k_conv_v15(
    const u16* __restrict__ xT, const u16* __restrict__ wT,
    const float* __restrict__ gg, const float* __restrict__ bbn,
    const float* __restrict__ mmn, const float* __restrict__ vvn,
    u16* __restrict__ yT,
    const float* __restrict__ gt, float* __restrict__ outp)
{
    __shared__ u16 lin[1600 * 8];        // 25.6 KB input halo chunk
    __shared__ u16 lwt[3][768 * 8];      // 3 x 12.3 KB: 3 taps x 64co x 32ci

    if (blockIdx.x >= 1080) {            // fused objects tail (conv1 launch)
        int ob = ((int)blockIdx.x - 1080) * 4 + ((int)threadIdx.x >> 6);
        obj_work(ob, threadIdx.x & 63, gt, outp);   // ob in [0, 2000)
        return;
    }

    int tid  = threadIdx.x;
    int wv   = tid >> 6, lane = tid & 63;
    int lm   = lane & 15, hi = lane >> 4;

    // XCD swizzle: 1080 conv blocks = 8 XCDs x 135 (bijective)
    int wg   = blockIdx.x;
    int wgid = (wg & 7) * 135 + (wg >> 3);
    int b    = wgid / 270;
    int rem  = wgid % 270;
    int row  = rem / 6;
    int t6   = rem % 6;
    int csp  = t6 % 3, cog = t6 / 3;
    int C0   = (csp == 2) ? 116 : csp * 64;
    int cob  = cog * 64;
    int R0   = row * 4;
    const u16* xb = xT + (size_t)b * PW_ * PW_ * CIN_;

    f32x4 acc[4][4];
#pragma unroll
    for (int i = 0; i < 4; ++i)
#pragma unroll
        for (int j = 0; j < 4; ++j) acc[i][j] = (f32x4){0.f, 0.f, 0.f, 0.f};

    unsigned soffI[6];
#pragma unroll
    for (int rd = 0; rd < 6; ++rd) {
        int o = rd * 256 + tid;
        int rc = o >> 2;
        int r = rc / 66, c = rc - 66 * r;
        int q = (o & 3) ^ ((c >> 1) & 3);
        soffI[rd] = (unsigned)(((R0 + r) * PW_ + (C0 + c)) * CIN_ + q * 8);
    }
    unsigned soffX = 0;
    if (tid < 64) {
        int o = 1536 + tid;
        int rc = o >> 2;
        int r = rc / 66, c = rc - 66 * r;
        if (o >= 1584) { r = 5; c = 65; }
        int q = (o & 3) ^ ((c >> 1) & 3);
        soffX = (unsigned)(((R0 + r) * PW_ + (C0 + c)) * CIN_ + q * 8);
    }
    const int wco = tid >> 2;
    const int wq  = (tid & 3) ^ ((wco >> 1) & 3);
    const unsigned soffW = (unsigned)((cob + wco) * CIN_ + wq * 8);

    #define STAGE_IN(CH)                                                        \
    {                                                                           \
        _Pragma("unroll")                                                       \
        for (int rd = 0; rd < 6; ++rd)                                          \
            GLOAD_LDS16(xb + soffI[rd] + (CH) * 32,                             \
                        &lin[(size_t)(rd * 256 + wv * 64) * 8]);                \
        if (tid < 64)                                                           \
            GLOAD_LDS16(xb + soffX + (CH) * 32, &lin[(size_t)1536 * 8]);        \
    }
    #define STAGE_W(NCH, NTG)                                                   \
    {                                                                           \
        _Pragma("unroll")                                                       \
        for (int rd = 0; rd < 3; ++rd)                                          \
            GLOAD_LDS16(wT + (size_t)((NTG) * 3 + rd) * CIN_ * CIN_ + soffW + (NCH) * 32, \
                        &lwt[NTG][(size_t)(rd * 256 + wv * 64) * 8]);           \
    }
    #define COMPUTE_TG(TG)                                                      \
    {                                                                           \
        _Pragma("unroll")                                                       \
        for (int t = 0; t < 3; ++t) {                                           \
            bf16x8 av[4];                                                       \
            _Pragma("unroll")                                                   \
            for (int mf = 0; mf < 4; ++mf) {                                    \
                int col = mf * 16 + lm;                                         \
                int unit = t * 256 + col * 4 + (hi ^ ((col >> 1) & 3));         \
                av[mf] = *(const bf16x8*)&lwt[TG][(size_t)unit * 8];            \
            }                                                                   \
            _Pragma("unroll")                                                   \
            for (int nf = 0; nf < 4; ++nf) {                                    \
                int c = wv * 16 + lm + t;                                       \
                int rc = (nf + (TG)) * 66 + c;                                  \
                int unit = rc * 4 + (hi ^ ((c >> 1) & 3));                      \
                bf16x8 bv = *(const bf16x8*)&lin[(size_t)unit * 8];             \
                _Pragma("unroll")                                               \
                for (int mf = 0; mf < 4; ++mf)                                  \
                    acc[mf][nf] = __builtin_amdgcn_mfma_f32_16x16x32_bf16(      \
                        av[mf], bv, acc[mf][nf], 0, 0, 0);                      \
            }                                                                   \
        }                                                                       \
    }

    STAGE_IN(0);
    STAGE_W(0, 0);

#pragma unroll
    for (int ch = 0; ch < 4; ++ch) {
#pragma unroll
        for (int tg = 0; tg < 3; ++tg) {
            if (tg == 0 && ch > 0) {
                __builtin_amdgcn_s_barrier();
                __builtin_amdgcn_sched_barrier(0);
                STAGE_IN(ch);
            }
            const bool last = (ch == 3 && tg == 2);
            if (!last) {
                const int nch = (tg == 2) ? ch + 1 : ch;
                const int ntg = (tg + 1) % 3;
                STAGE_W(nch, ntg);
                asm volatile("s_waitcnt vmcnt(3)" ::: "memory");
            } else {
                asm volatile("s_waitcnt vmcnt(0)" ::: "memory");
            }
            __builtin_amdgcn_s_barrier();
            __builtin_amdgcn_sched_barrier(0);
            COMPUTE_TG(tg);
        }
    }
    #undef STAGE_IN
    #undef STAGE_W
    #undef COMPUTE_TG

#pragma unroll
    for (int mf = 0; mf < 4; ++mf) {
        int co0 = cob + mf * 16 + hi * 4;
        float4 g4 = *(const float4*)(gg + co0);
        float4 b4 = *(const float4*)(bbn + co0);
        float4 m4 = *(const float4*)(mmn + co0);
        float4 v4 = *(const float4*)(vvn + co0);
        float sc0 = g4.x / sqrtf(v4.x + 1e-5f), sh0 = b4.x - m4.x * sc0;
        float sc1 = g4.y / sqrtf(v4.y + 1e-5f), sh1 = b4.y - m4.y * sc1;
        float sc2 = g4.z / sqrtf(v4.z + 1e-5f), sh2 = b4.z - m4.z * sc2;
        float sc3 = g4.w / sqrtf(v4.w + 1e-5f), sh3 = b4.w - m4.w * sc3;
#pragma unroll
        for (int nf = 0; nf < 4; ++nf) {
            f32x4 A = acc[mf][nf];
            float y0 = fmaxf(fmaf(A[0], sc0, sh0), 0.f);
            float y1 = fmaxf(fmaf(A[1], sc1, sh1), 0.f);
            float y2 = fmaxf(fmaf(A[2], sc2, sh2), 0.f);
            float y3 = fmaxf(fmaf(A[3], sc3, sh3), 0.f);
            unsigned p0 = (unsigned)f2bf(y0) | ((unsigned)f2bf(y1) << 16);
            unsigned p1 = (unsigned)f2bf(y2) | ((unsigned)f2bf(y3) << 16);
            u16* op = yT + (size_t)b * PW_ * PW_ * CIN_ +
                      ((size_t)(R0 + nf + 1) * PW_ + (C0 + wv * 16 + lm + 1)) * CIN_ + co0;
            *(uint2*)op = make_uint2(p0, p1);
        }
    }
}

// ---------------------------------------------------------------------------
// head: 2 hm + 9 reg (co padded to 16), validated structure + fused
// heatmap_mask epilogue (objects completes inside conv1, before this).
// ---------------------------------------------------------------------------
__global__ __launch_bounds__(256) void k_head_v9(
    const u16* __restrict__ f2T, const u16* __restrict__ wTh,
    const float* __restrict__ hb, const float* __restrict__ rb,
    float* __restrict__ out)
{
    __shared__ u16 lin[1600 * 8];
    __shared__ u16 lwt[2304 * 8];        // [tap][co16][16 ci-units swz]

    int tid  = threadIdx.x;
    int wv   = tid >> 6, lane = tid & 63;
    int lm   = lane & 15, hi = lane >> 4;
    int csp  = blockIdx.x;
    int C0   = (csp == 2) ? 116 : csp * 64;
    int R0   = blockIdx.y * 4;
    int b    = blockIdx.z;
    const u16* xb = f2T + (size_t)b * PW_ * PW_ * CIN_;

    f32x4 acc[4];
#pragma unroll
    for (int i = 0; i < 4; ++i) acc[i] = (f32x4){0.f, 0.f, 0.f, 0.f};

#pragma unroll
    for (int rd = 0; rd < 9; ++rd) {
        int o = rd * 256 + tid;
        int tap = o >> 8, rest = o & 255;
        int co = rest >> 4, u8s = rest & 15;
        const u16* src = wTh + (size_t)tap * 16 * CIN_ + co * CIN_ + ((u8s ^ (co & 7)) * 8);
        GLOAD_LDS16(src, &lwt[(size_t)(rd * 256 + wv * 64) * 8]);
    }

#pragma unroll 1
    for (int ch = 0; ch < 4; ++ch) {
        int ci0 = ch * 32;
        __syncthreads();
#pragma unroll
        for (int rd = 0; rd < 6; ++rd) {
            int o = rd * 256 + tid;
            int rc = o >> 2;
            int r = rc / 66, c = rc - 66 * r;
            int q = (o & 3) ^ ((c >> 1) & 3);
            const u16* src = xb + ((size_t)(R0 + r) * PW_ + (C0 + c)) * CIN_ + ci0 + q * 8;
            GLOAD_LDS16(src, &lin[(size_t)(rd * 256 + wv * 64) * 8]);
        }
        if (tid < 64) {
            int o = 1536 + tid;
            int rc = o >> 2;
            int r = rc / 66, c = rc - 66 * r;
            if (o >= 1584) { r = 5; c = 65; }
            int q = (o & 3) ^ ((c >> 1) & 3);
            const u16* src = xb + ((size_t)(R0 + r) * PW_ + (C0 + c)) * CIN_ + ci0 + q * 8;
            GLOAD_LDS16(src, &lin[(size_t)1536 * 8]);
        }
        __syncthreads();

#pragma unroll
        for (int tap = 0; tap < 9; ++tap) {
            const int kr = tap / 3, kc = tap - 3 * (tap / 3);
            int u8 = (ch * 4 + hi) ^ (lm & 7);
            bf16x8 av = *(const bf16x8*)&lwt[(size_t)(tap * 256 + lm * 16 + u8) * 8];
#pragma unroll
            for (int nf = 0; nf < 4; ++nf) {
                int c = wv * 16 + lm + kc;
                int rc = (nf + kr) * 66 + c;
                int unit = rc * 4 + (hi ^ ((c >> 1) & 3));
                bf16x8 bv = *(const bf16x8*)&lin[(size_t)unit * 8];
                acc[nf] = __builtin_amdgcn_mfma_f32_16x16x32_bf16(av, bv, acc[nf], 0, 0, 0);
            }
        }
    }

#pragma unroll
    for (int nf = 0; nf < 4; ++nf) {
        int row = R0 + nf, col = C0 + wv * 16 + lm;
        f32x4 A = acc[nf];
#pragma unroll
        for (int r = 0; r < 4; ++r) {
            int co = hi * 4 + r;
            float v = A[r];
            if (co < 2)
                out[HM_OFF + ((size_t)(b * 2 + co)) * HW_ + (size_t)row * FW_ + col] = v + hb[co];
            else if (co < 11)
                out[REG_OFF + ((size_t)(b * 9 + co - 2)) * HW_ + (size_t)row * FW_ + col] = v + rb[co - 2];
        }
    }

    // fused heatmap_mask: 540 blocks x 480 elems = 259200 exactly
    int blk = (b * 45 + (int)blockIdx.y) * 3 + csp;
    int base = blk * 480;
    for (int i = base + tid; i < base + 480; i += 256) {
        float v = out[HEAT_OFF + i];
        out[HMM_OFF + i] = v > 0.f ? 1.f : 0.f;
    }
}

// ---------------------------------------------------------------------------
extern "C" void kernel_launch(void* const* d_in, const int* in_sizes, int n_in,
                              void* d_out, int out_size, void* d_ws, size_t ws_size,
                              hipStream_t stream)
{
    const float* x  = (const float*)d_in[0];
    const float* gt = (const float*)d_in[1];
    const float* w1 = (const float*)d_in[2];
    const float* g1 = (const float*)d_in[3];
    const float* b1 = (const float*)d_in[4];
    const float* m1 = (const float*)d_in[5];
    const float* v1 = (const float*)d_in[6];
    const float* w2 = (const float*)d_in[7];
    const float* g2 = (const float*)d_in[8];
    const float* b2 = (const float*)d_in[9];
    const float* m2 = (const float*)d_in[10];
    const float* v2 = (const float*)d_in[11];
    const float* hw = (const float*)d_in[12];
    const float* hb = (const float*)d_in[13];
    const float* rw = (const float*)d_in[14];
    const float* rb = (const float*)d_in[15];
    float* out = (float*)d_out;

    u16* ws  = (u16*)d_ws;
    u16* xT  = ws;
    u16* f1T = ws + PADE;
    u16* f2T = ws + 2 * PADE;
    u16* wT1 = ws + 3 * PADE;
    u16* wT2 = wT1 + 9 * CIN_ * CIN_;
    u16* wTh = wT2 + 9 * CIN_ * CIN_;

    // pre-pass: 720 transpose blocks + flat-work blocks
    const int NFLAT = 12 * 724 + BB_ * 2 * HW_ + 2 * 9 * CIN_ * CIN_ + 9 * 16 * CIN_;
    const int NPRE  = 720 + (NFLAT + 255) / 256;
    k_pre<<<NPRE, 256, 0, stream>>>(x, xT, ws, out, w1, w2, hw, rw, wT1, wT2, wTh);

    // conv1 + fused objects tail: 500 blocks x 4 waves = 2000 objects
    k_conv_v15<<<1080 + 500, 256, 0, stream>>>(xT,  wT1, g1, b1, m1, v1, f1T, gt, out);
    // conv2 (no tail)
    k_conv_v15<<<1080,       256, 0, stream>>>(f1T, wT2, g2, b2, m2, v2, f2T, gt, out);

    dim3 hg(3, 45, BB_);
    k_head_v9<<<hg, 256, 0, stream>>>(f2T, wTh, hb, rb, out);
}